// Round 10
// baseline (275.769 us; speedup 1.0000x reference)
//
#include <hip/hip_runtime.h>

// DiffPooling on MI355X (gfx950).
// outputs f32 concat: features_pooled (256x512), assignments (8192x256),
// adjacency_pooled (256x256), link_loss, ent_loss.
// link_loss: ||A - sp sp^T||_F^2 = sum(A^2) - 2*tr(adj_pooled) + ||sp^T sp||_F^2
//
// MFMA A-operands in "panel" format (stride-32 u16 rows, gll-linear):
//   offset_u16(p, m, k) = (p*256 + m)*32 + (k%32),  p = global_k/32
// G2+G4+G5 run as ONE mega-kernel (block-range roles; shared A = spTpan).
// G2 writes bf16 partials DIRECTLY as panels; G3 consumes the 8 parts as one
// Kin=65536 panel-A GEMM with B-row = kq & 8191 (linearity of A_pool).

typedef unsigned short u16;
typedef __bf16 bf16x8 __attribute__((ext_vector_type(8)));
typedef float f32x4 __attribute__((ext_vector_type(4)));
typedef float float8_t __attribute__((ext_vector_type(8)));
typedef unsigned short ushort8_t __attribute__((ext_vector_type(8)));

#define Nn 8192
#define Dd 512
#define Kk 256

__device__ __forceinline__ u16 f2bf(float f) {
  unsigned int u = __builtin_bit_cast(unsigned int, f);
  u += 0x7FFFu + ((u >> 16) & 1u);   // RNE
  return (u16)(u >> 16);
}
__device__ __forceinline__ void gll16(const void* g, void* l) {
  __builtin_amdgcn_global_load_lds(
      (const __attribute__((address_space(1))) unsigned int*)g,
      (__attribute__((address_space(3))) unsigned int*)l, 16, 0, 0);
}

template <bool B> struct BRegSel { typedef float8_t T; };
template <> struct BRegSel<true> { typedef ushort8_t T; };

// ---------------- templated panel-A GEMM (G1, G3) ----------------
// C(256 x 64 per block) = Apanel @ B; counted-vmcnt pipeline.
template <bool BF16B, bool MODB, int OCC>
__launch_bounds__(256, OCC)
__global__ void gemm2(const u16* __restrict__ Apan, int ppmb,
                      const void* __restrict__ Bv, int ldb,
                      float* __restrict__ Cv, int ldc,
                      int kchunk, size_t zstride, int swz) {
  __shared__ alignas(16) u16 SH[2 * 8192 + 2 * 2048];  // 40960 B

  int bx = blockIdx.x, bz = blockIdx.z;
  if (swz) {
    int gx = gridDim.x, tot = gx * gridDim.z;
    int f = bx + gx * bz;
    int l = (f & 7) * (tot >> 3) + (f >> 3);
    bx = l % gx; bz = l / gx;
  }
  const int tid = threadIdx.x, wv = tid >> 6, lane = tid & 63;
  const int l15 = lane & 15, g = lane >> 4;
  const int col0 = bx * 64;
  const int row0 = blockIdx.y * 256;
  const int kbeg = bz * kchunk;
  const int steps = kchunk >> 5;
  const u16* pbase = Apan + (size_t)(blockIdx.y * ppmb + (kbeg >> 5)) * 8192;

  typename BRegSel<BF16B>::T rb;

  auto loadB = [&](int t) {
    int kq = kbeg + t * 32 + wv * 8;
    if constexpr (MODB) kq &= (Nn - 1);
    if constexpr (BF16B) {
      const u16* p = (const u16*)Bv + (size_t)kq * ldb + col0 + lane;
#pragma unroll
      for (int i = 0; i < 8; ++i) rb[i] = p[(size_t)i * ldb];
    } else {
      const float* p = (const float*)Bv + (size_t)kq * ldb + col0 + lane;
#pragma unroll
      for (int i = 0; i < 8; ++i) rb[i] = p[(size_t)i * ldb];
    }
  };
  auto storeB = [&](int buf) {
    ushort8_t h;
    if constexpr (BF16B) {
      h = rb;
    } else {
#pragma unroll
      for (int i = 0; i < 8; ++i) h[i] = f2bf(rb[i]);
    }
    *(uint4*)&SH[16384 + buf * 2048 + lane * 32 + wv * 8] = __builtin_bit_cast(uint4, h);
  };
  auto gllA = [&](int buf, int t) {
    const char* gp = (const char*)(pbase + (size_t)t * 8192) + wv * 4096 + lane * 16;
    char* lp = (char*)&SH[buf * 8192] + wv * 4096;
#pragma unroll
    for (int r = 0; r < 4; ++r) gll16(gp + r * 1024, lp + r * 1024);
  };

  f32x4 acc[4][4];
#pragma unroll
  for (int i = 0; i < 4; ++i)
#pragma unroll
    for (int j = 0; j < 4; ++j) acc[i][j] = (f32x4){0.f, 0.f, 0.f, 0.f};

  auto comp = [&](int buf) {
    const u16* as = &SH[buf * 8192];
    const u16* bs = &SH[16384 + buf * 2048];
    bf16x8 afr[4], bfr[4];
#pragma unroll
    for (int j = 0; j < 4; ++j)
      bfr[j] = *(const bf16x8*)(bs + (j * 16 + l15) * 32 + g * 8);
#pragma unroll
    for (int i = 0; i < 4; ++i)
      afr[i] = *(const bf16x8*)(as + (wv * 64 + i * 16 + l15) * 32 + g * 8);
#pragma unroll
    for (int i = 0; i < 4; ++i)
#pragma unroll
      for (int j = 0; j < 4; ++j)
        acc[i][j] = __builtin_amdgcn_mfma_f32_16x16x32_bf16(afr[i], bfr[j], acc[i][j], 0, 0, 0);
  };

  gllA(0, 0);
  loadB(0);
  const int last = steps - 1;
  for (int t = 0; t < steps; ++t) {
    const int cur = t & 1;
    gllA(1 - cur, (t + 1 < last) ? t + 1 : last);
    storeB(cur);
    loadB((t + 1 < last) ? t + 1 : last);
    asm volatile("s_waitcnt vmcnt(12) lgkmcnt(0)" ::: "memory");
    __builtin_amdgcn_s_barrier();
    __builtin_amdgcn_sched_barrier(0);
    comp(cur);
    __builtin_amdgcn_sched_barrier(0);
    __builtin_amdgcn_s_barrier();
  }
  asm volatile("s_waitcnt vmcnt(0) lgkmcnt(0)" ::: "memory");
  __builtin_amdgcn_s_barrier();

  // f32 store via LDS, two 128-row halves
  float* Cz = Cv + (size_t)bz * zstride;
  float* sf = (float*)SH;              // [128][68] f32
#pragma unroll
  for (int h = 0; h < 2; ++h) {
    __syncthreads();
    if ((wv >> 1) == h) {
#pragma unroll
      for (int i = 0; i < 4; ++i)
#pragma unroll
        for (int j = 0; j < 4; ++j)
#pragma unroll
          for (int r = 0; r < 4; ++r)
            sf[((wv & 1) * 64 + i * 16 + g * 4 + r) * 68 + j * 16 + l15] = acc[i][j][r];
    }
    __syncthreads();
#pragma unroll
    for (int e = 0; e < 8; ++e) {
      int idx2 = tid + e * 256;
      int m = idx2 >> 4, c4 = (idx2 & 15) * 4;
      float4 v = *(const float4*)(sf + m * 68 + c4);
      *(float4*)(Cz + (size_t)(row0 + h * 128 + m) * ldc + col0 + c4) = v;
    }
  }
}

// ---------------- mega kernel: G2 (1024) + G4 (128) + G5 (64) ----------------
__launch_bounds__(256, 4)
__global__ void gemm_mega(const u16* __restrict__ spTpan,
                          const float* __restrict__ Adj, u16* __restrict__ parts,
                          float* __restrict__ sumsq,
                          const float* __restrict__ F, float* __restrict__ fp_part,
                          const u16* __restrict__ spb, float* __restrict__ ss_part) {
  __shared__ alignas(16) u16 SH[2 * 8192 + 2 * 2048];
  float* sred = (float*)&SH[20472];

  const int b = blockIdx.x;
  int role, bx, bz, ldb, kchunk, ldc;
  const void* Bv;
  bool isb16;
  if (b < 1024) {                       // G2: P-partials = spT @ Adj
    role = 0;
    int l = (b & 7) * 128 + (b >> 3);   // XCD-chunked remap within 1024
    bx = l % 128; bz = l / 128;
    Bv = Adj; ldb = Nn; isb16 = false; kchunk = 1024; ldc = 0;
  } else if (b < 1152) {                // G4: fp_part = spT @ F
    role = 1;
    int lb = b - 1024;
    bx = lb & 7; bz = lb >> 3;
    Bv = F; ldb = Dd; isb16 = false; kchunk = 512; ldc = Dd;
  } else {                              // G5: ss_part = spT @ sp
    role = 2;
    int lb = b - 1152;
    bx = lb & 3; bz = lb >> 2;
    Bv = spb; ldb = Kk; isb16 = true; kchunk = 512; ldc = Kk;
  }
  const int tid = threadIdx.x, wv = tid >> 6, lane = tid & 63;
  const int l15 = lane & 15, g = lane >> 4;
  const int col0 = bx * 64;
  const int kbeg = bz * kchunk;
  const int steps = kchunk >> 5;
  const u16* pbase = spTpan + (size_t)(kbeg >> 5) * 8192;

  float ss = 0.f;
  float8_t rbf;
  ushort8_t rbu;

  auto loadB = [&](int t) {
    const int kq = kbeg + t * 32 + wv * 8;
    if (isb16) {
      const u16* p = (const u16*)Bv + (size_t)kq * ldb + col0 + lane;
#pragma unroll
      for (int i = 0; i < 8; ++i) rbu[i] = p[(size_t)i * ldb];
    } else {
      const float* p = (const float*)Bv + (size_t)kq * ldb + col0 + lane;
#pragma unroll
      for (int i = 0; i < 8; ++i) rbf[i] = p[(size_t)i * ldb];
    }
  };
  auto storeB = [&](int buf) {
    ushort8_t h;
    if (isb16) {
      h = rbu;
    } else {
#pragma unroll
      for (int i = 0; i < 8; ++i) {
        h[i] = f2bf(rbf[i]);
        if (role == 0) ss += rbf[i] * rbf[i];
      }
    }
    *(uint4*)&SH[16384 + buf * 2048 + lane * 32 + wv * 8] = __builtin_bit_cast(uint4, h);
  };
  auto gllA = [&](int buf, int t) {
    const char* gp = (const char*)(pbase + (size_t)t * 8192) + wv * 4096 + lane * 16;
    char* lp = (char*)&SH[buf * 8192] + wv * 4096;
#pragma unroll
    for (int r = 0; r < 4; ++r) gll16(gp + r * 1024, lp + r * 1024);
  };

  f32x4 acc[4][4];
#pragma unroll
  for (int i = 0; i < 4; ++i)
#pragma unroll
    for (int j = 0; j < 4; ++j) acc[i][j] = (f32x4){0.f, 0.f, 0.f, 0.f};

  auto comp = [&](int buf) {
    const u16* as = &SH[buf * 8192];
    const u16* bs = &SH[16384 + buf * 2048];
    bf16x8 afr[4], bfr[4];
#pragma unroll
    for (int j = 0; j < 4; ++j)
      bfr[j] = *(const bf16x8*)(bs + (j * 16 + l15) * 32 + g * 8);
#pragma unroll
    for (int i = 0; i < 4; ++i)
      afr[i] = *(const bf16x8*)(as + (wv * 64 + i * 16 + l15) * 32 + g * 8);
#pragma unroll
    for (int i = 0; i < 4; ++i)
#pragma unroll
      for (int j = 0; j < 4; ++j)
        acc[i][j] = __builtin_amdgcn_mfma_f32_16x16x32_bf16(afr[i], bfr[j], acc[i][j], 0, 0, 0);
  };

  gllA(0, 0);
  loadB(0);
  const int last = steps - 1;
  for (int t = 0; t < steps; ++t) {
    const int cur = t & 1;
    gllA(1 - cur, (t + 1 < last) ? t + 1 : last);
    storeB(cur);
    loadB((t + 1 < last) ? t + 1 : last);
    asm volatile("s_waitcnt vmcnt(12) lgkmcnt(0)" ::: "memory");
    __builtin_amdgcn_s_barrier();
    __builtin_amdgcn_sched_barrier(0);
    comp(cur);
    __builtin_amdgcn_sched_barrier(0);
    __builtin_amdgcn_s_barrier();
  }
  asm volatile("s_waitcnt vmcnt(0) lgkmcnt(0)" ::: "memory");
  __builtin_amdgcn_s_barrier();

  if (role == 0) {
    // bf16 partial in PANEL format: part z, off = ((col/32)*256+m)*32 + col%32
    u16* C = parts + (size_t)bz * ((size_t)Kk * Nn);
    u16* sb = SH;                        // [256][72]
#pragma unroll
    for (int i = 0; i < 4; ++i)
#pragma unroll
      for (int j = 0; j < 4; ++j)
#pragma unroll
        for (int r = 0; r < 4; ++r)
          sb[(wv * 64 + i * 16 + g * 4 + r) * 72 + j * 16 + l15] = f2bf(acc[i][j][r]);
    __syncthreads();
    int c8 = tid & 7;
    size_t pb = (size_t)((col0 >> 5) + (c8 >> 2)) * 8192 + (c8 & 3) * 8;
#pragma unroll
    for (int e = 0; e < 8; ++e) {
      int m = (tid >> 3) + e * 32;
      uint4 v = *(const uint4*)(sb + m * 72 + c8 * 8);
      *(uint4*)(C + pb + (size_t)m * 32) = v;
    }
    // fused sum(A^2)
#pragma unroll
    for (int o = 32; o; o >>= 1) ss += __shfl_xor(ss, o);
    __syncthreads();
    if (lane == 0) sred[wv] = ss;
    __syncthreads();
    if (tid == 0) atomicAdd(sumsq, sred[0] + sred[1] + sred[2] + sred[3]);
  } else {
    float* Cz = (role == 1 ? fp_part + (size_t)bz * 131072
                           : ss_part + (size_t)bz * 65536);
    float* sf = (float*)SH;              // [128][68]
#pragma unroll
    for (int h = 0; h < 2; ++h) {
      __syncthreads();
      if ((wv >> 1) == h) {
#pragma unroll
        for (int i = 0; i < 4; ++i)
#pragma unroll
          for (int j = 0; j < 4; ++j)
#pragma unroll
            for (int r = 0; r < 4; ++r)
              sf[((wv & 1) * 64 + i * 16 + g * 4 + r) * 68 + j * 16 + l15] = acc[i][j][r];
      }
      __syncthreads();
#pragma unroll
      for (int e = 0; e < 8; ++e) {
        int idx2 = tid + e * 256;
        int m = idx2 >> 4, c4 = (idx2 & 15) * 4;
        float4 v = *(const float4*)(sf + m * 68 + c4);
        *(float4*)(Cz + (size_t)(h * 128 + m) * ldc + col0 + c4) = v;
      }
    }
  }
}

// ---------------- producers / small kernels ----------------
__launch_bounds__(256)
__global__ void cvtF_panel(const float* __restrict__ F, u16* __restrict__ pan,
                           float* __restrict__ cs, float* __restrict__ scal) {
  if (blockIdx.x == 2048) {
    int t = threadIdx.x;
    float4 z = {0.f, 0.f, 0.f, 0.f};
    if (t < 64) ((float4*)cs)[t] = z;
    else if (t < 66) ((float4*)scal)[t - 64] = z;   // scal[0..7]
    return;
  }
  int idx = blockIdx.x * 256 + threadIdx.x;
  int m = idx >> 6, k0 = (idx & 63) * 8;
  float4 a = *(const float4*)(F + (size_t)m * Dd + k0);
  float4 b = *(const float4*)(F + (size_t)m * Dd + k0 + 4);
  ushort8_t h;
  h[0] = f2bf(a.x); h[1] = f2bf(a.y); h[2] = f2bf(a.z); h[3] = f2bf(a.w);
  h[4] = f2bf(b.x); h[5] = f2bf(b.y); h[6] = f2bf(b.z); h[7] = f2bf(b.w);
  int mb = m >> 8, mr = m & 255, p = k0 >> 5, c = k0 & 31;
  *(uint4*)(pan + ((size_t)(mb * 16 + p) * 256 + mr) * 32 + c) = __builtin_bit_cast(uint4, h);
}

__launch_bounds__(256)
__global__ void softmax_rows(float* __restrict__ io, const float* __restrict__ bias) {
  int wv = threadIdx.x >> 6, lane = threadIdx.x & 63;
  int n = blockIdx.x * 4 + wv;
  float4 b4 = ((const float4*)bias)[lane];
  float4 x = ((const float4*)(io + (size_t)n * Kk))[lane];
  x.x += b4.x; x.y += b4.y; x.z += b4.z; x.w += b4.w;
  float m = fmaxf(fmaxf(x.x, x.y), fmaxf(x.z, x.w));
#pragma unroll
  for (int o = 32; o; o >>= 1) m = fmaxf(m, __shfl_xor(m, o));
  float4 e = {__expf(x.x - m), __expf(x.y - m), __expf(x.z - m), __expf(x.w - m)};
  float s = e.x + e.y + e.z + e.w;
#pragma unroll
  for (int o = 32; o; o >>= 1) s += __shfl_xor(s, o);
  float inv = 1.f / s;
  e.x *= inv; e.y *= inv; e.z *= inv; e.w *= inv;
  ((float4*)(io + (size_t)n * Kk))[lane] = e;
}

__launch_bounds__(256)
__global__ void colsum_k(const float* __restrict__ a, float* __restrict__ cs) {
  __shared__ float4 red[4][64];
  int t = threadIdx.x, rg = t >> 6, c = t & 63;
  size_t n0 = (size_t)blockIdx.x * 128 + rg * 32;
  float4 s = {0.f, 0.f, 0.f, 0.f};
  for (int i = 0; i < 32; ++i) {
    float4 v = ((const float4*)(a + (n0 + i) * Kk))[c];
    s.x += v.x; s.y += v.y; s.z += v.z; s.w += v.w;
  }
  red[rg][c] = s;
  __syncthreads();
  if (rg == 0) {
    float4 a1 = red[1][c], a2 = red[2][c], a3 = red[3][c];
    s.x += a1.x + a2.x + a3.x; s.y += a1.y + a2.y + a3.y;
    s.z += a1.z + a2.z + a3.z; s.w += a1.w + a2.w + a3.w;
    atomicAdd(&cs[c * 4 + 0], s.x); atomicAdd(&cs[c * 4 + 1], s.y);
    atomicAdd(&cs[c * 4 + 2], s.z); atomicAdd(&cs[c * 4 + 3], s.w);
  }
}

__launch_bounds__(256)
__global__ void make_sp_all(const float* __restrict__ a, const float* __restrict__ cs,
                            u16* __restrict__ spb, u16* __restrict__ pan,
                            float* __restrict__ ent_sum) {
  __shared__ float sr[4];
  int p = blockIdx.x, k = threadIdx.x;
  float inv = 1.f / (cs[k] + 1e-8f);
  int n0 = p * 32;
  float ent = 0.f;
  ushort8_t h[4];
#pragma unroll
  for (int q = 0; q < 4; ++q) {
#pragma unroll
    for (int j = 0; j < 8; ++j) {
      float v = a[(size_t)(n0 + q * 8 + j) * Kk + k] * inv;
      u16 hb = f2bf(v);
      h[q][j] = hb;
      ent -= v * __logf(v + 1e-15f);
      spb[(size_t)(n0 + q * 8 + j) * Kk + k] = hb;
    }
  }
  u16* dst = pan + ((size_t)p * 256 + k) * 32;
  *(uint4*)(dst + 0)  = __builtin_bit_cast(uint4, h[0]);
  *(uint4*)(dst + 8)  = __builtin_bit_cast(uint4, h[1]);
  *(uint4*)(dst + 16) = __builtin_bit_cast(uint4, h[2]);
  *(uint4*)(dst + 24) = __builtin_bit_cast(uint4, h[3]);
#pragma unroll
  for (int o = 32; o; o >>= 1) ent += __shfl_xor(ent, o);
  if ((k & 63) == 0) sr[k >> 6] = ent;
  __syncthreads();
  if (k == 0) atomicAdd(ent_sum, sr[0] + sr[1] + sr[2] + sr[3]);
}

// combine partials + inline finalize (last-block pattern).
// blocks 0-511: fpool (16 slices); 512-767: frob(spTsp) (16); 768-1023: apool (32) + trace.
__launch_bounds__(256)
__global__ void combine3(const float* __restrict__ fp_part, const float* __restrict__ ss_part,
                         const float* __restrict__ ap_part,
                         float* __restrict__ fpool, float* __restrict__ apool,
                         float* __restrict__ scal,
                         float* __restrict__ olink, float* __restrict__ oent) {
  __shared__ float sr[4];
  __shared__ int lastS;
  int b = blockIdx.x, t = threadIdx.x;
  if (b < 512) {
    int i = b * 256 + t;
    float s = 0.f;
#pragma unroll
    for (int z = 0; z < 16; ++z) s += fp_part[z * 131072 + i];
    fpool[i] = s;
  } else if (b < 768) {
    int i = (b - 512) * 256 + t;
    float s = 0.f;
#pragma unroll
    for (int z = 0; z < 16; ++z) s += ss_part[z * 65536 + i];
    float q = s * s;
#pragma unroll
    for (int o = 32; o; o >>= 1) q += __shfl_xor(q, o);
    if ((t & 63) == 0) sr[t >> 6] = q;
    __syncthreads();
    if (t == 0) atomicAdd(&scal[2], sr[0] + sr[1] + sr[2] + sr[3]);
  } else {
    int i = (b - 768) * 256 + t;
    float s = 0.f;
#pragma unroll
    for (int z = 0; z < 32; ++z) s += ap_part[z * 65536 + i];
    apool[i] = s;
    if (i % 257 == 0) atomicAdd(&scal[3], s);
  }
  // last-block finalize
  __threadfence();
  if (t == 0) {
    int* cnt = (int*)&scal[4];
    lastS = (atomicAdd(cnt, 1) == 1023);
  }
  __syncthreads();
  if (lastS && t == 0) {
    __threadfence();
    volatile float* sc = scal;
    float val = sc[0] - 2.f * sc[3] + sc[2];
    *olink = sqrtf(fmaxf(val, 0.f)) / ((float)Nn * (float)Nn);
    *oent  = sc[1] / (float)Nn;
  }
}

// ---------------- launch ----------------
extern "C" void kernel_launch(void* const* d_in, const int* in_sizes, int n_in,
                              void* d_out, int out_size, void* d_ws, size_t ws_size,
                              hipStream_t stream) {
  const float* F    = (const float*)d_in[0];
  const float* Adj  = (const float*)d_in[1];
  const float* W    = (const float*)d_in[2];
  const float* bias = (const float*)d_in[3];
  float* out = (float*)d_out;
  char* ws = (char*)d_ws;

  u16*  FbfPan  = (u16*)(ws + 0);            // 8 MB (dead after G1)
  u16*  parts   = (u16*)(ws + 0);            // 8 x 4 MB bf16 G2 panel-partials
  u16*  spb     = (u16*)(ws + 33554432);     // 4 MB
  u16*  spTpan  = (u16*)(ws + 37748736);     // 4 MB
  float* fp_part = (float*)(ws + 41943040);  // 8 MB (16 x 131072)
  float* ss_part = (float*)(ws + 50331648);  // 4 MB (16 x 65536)
  float* ap_part = (float*)(ws + 54525952);  // 8 MB (32 x 65536)
  float* cs     = (float*)(ws + 62914560);   // 1 KB
  float* scal   = (float*)(ws + 62915584);   // [0]sumA2 [1]ent [2]frob [3]trace [4]cnt

  float* fpool  = out;
  float* assign = out + 131072;
  float* apool  = out + 2228224;
  float* olink  = out + 2293760;
  float* oent   = out + 2293761;

  cvtF_panel<<<2049, 256, 0, stream>>>(F, FbfPan, cs, scal);

  // G1: logits = F @ W -> assign, softmax in place
  gemm2<false, false, 2><<<dim3(4, 32, 1), 256, 0, stream>>>(
      FbfPan, 16, W, Kk, assign, Kk, Dd, 0, 0);
  softmax_rows<<<2048, 256, 0, stream>>>(assign, bias);
  colsum_k<<<64, 256, 0, stream>>>(assign, cs);
  make_sp_all<<<256, 256, 0, stream>>>(assign, cs, spb, spTpan, &scal[1]);

  // mega: G2 (P panel-partials + sumA2) + G4 (fp_part) + G5 (ss_part)
  gemm_mega<<<1216, 256, 0, stream>>>(spTpan, Adj, parts, &scal[0],
                                      F, fp_part, spb, ss_part);

  // G3: apool partials = [parts] @ [sp;...;sp]  (Kin = 65536, B-row = kq & 8191)
  gemm2<true, true, 2><<<dim3(4, 1, 32), 256, 0, stream>>>(
      parts, 0, spb, Kk, ap_part, Kk, 65536 / 32, 65536, 1);

  combine3<<<1024, 256, 0, stream>>>(fp_part, ss_part, ap_part, fpool, apool,
                                     scal, olink, oent);
}